// Round 1
// baseline (590.101 us; speedup 1.0000x reference)
//
#include <hip/hip_runtime.h>

typedef unsigned int u32;
typedef unsigned short u16;

#define NN 8192
#define FIN 512
#define FOUT 128
#define NH 16

typedef float f32x16 __attribute__((ext_vector_type(16)));
typedef __bf16 bf16x8 __attribute__((ext_vector_type(8)));

union PackAB { u32 u[4]; bf16x8 v; };

__device__ __forceinline__ u32 rne_hi(u32 u) {
  // round-to-nearest-even bf16: add 0x7FFF + lsb of result half
  return u + (0x7FFFu + ((u >> 16) & 1u));
}
__device__ __forceinline__ u16 f32_to_bf16(float f) {
  u32 u = __float_as_uint(f);
  return (u16)(rne_hi(u) >> 16);
}

// ---------------- K0: WT = bf16(W^T) [128][512]; w1s[k][f] = w1[k][f]+w1[k][128+f]
__global__ __launch_bounds__(256) void prep_kernel(
    const float* __restrict__ W, const float* __restrict__ w1,
    u16* __restrict__ WT, float* __restrict__ w1s) {
  int b = blockIdx.x, t = threadIdx.x;
  if (b < 256) {
    int o = b * 256 + t;          // [0, 65536)
    int n = o >> 9, k = o & 511;  // WT[n][k] = W[k][n]
    WT[o] = f32_to_bf16(W[k * FOUT + n]);
  } else {
    for (int e = t; e < NH * FOUT; e += 256) {
      int k = e >> 7, f = e & 127;
      w1s[e] = w1[k * 256 + f] + w1[k * 256 + 128 + f];
    }
  }
}

// ---------------- K1: h = x@W via 32x32x16 bf16 MFMA (32-row tile / block).
// Epilogue: write HT bf16 [128][8192]; fused attention-net -> qpart[block].
__global__ __launch_bounds__(256) void h_kernel(
    const float* __restrict__ x, const u16* __restrict__ WT,
    const float* __restrict__ b1, const float* __restrict__ w21,
    const float* __restrict__ b21, const float* __restrict__ w22,
    const float* __restrict__ b22, const float* __restrict__ w1s,
    u16* __restrict__ HT, float* __restrict__ qpart) {
  __shared__ u16 hs[32][FOUT + 8];     // +8 u16 pad: breaks 8-way bank conflict
  __shared__ float w1l[NH][FOUT + 4];  // +4 f32 pad
  __shared__ float us[32][NH + 1];
  int t = threadIdx.x;
  int w = t >> 6, l = t & 63;
  int m = l & 31, kh = l >> 5;         // A row / k-half per 32x32x16 frag layout
  int i0 = blockIdx.x * 32;
  const float* ap = x + (i0 + m) * FIN + kh * 8;
  const u16* bp = WT + (w * 32 + m) * FIN + kh * 8;
  f32x16 acc;
#pragma unroll
  for (int r = 0; r < 16; ++r) acc[r] = 0.0f;
#pragma unroll 2
  for (int kc = 0; kc < FIN; kc += 16) {
    float4 a0 = *(const float4*)ap;
    float4 a1 = *(const float4*)(ap + 4);
    uint4 bb = *(const uint4*)bp;
    ap += 16; bp += 16;
    u32 f0 = rne_hi(__float_as_uint(a0.x));
    u32 f1 = rne_hi(__float_as_uint(a0.y));
    u32 f2 = rne_hi(__float_as_uint(a0.z));
    u32 f3 = rne_hi(__float_as_uint(a0.w));
    u32 f4 = rne_hi(__float_as_uint(a1.x));
    u32 f5 = rne_hi(__float_as_uint(a1.y));
    u32 f6 = rne_hi(__float_as_uint(a1.z));
    u32 f7 = rne_hi(__float_as_uint(a1.w));
    PackAB pa, pb;
    pa.u[0] = (f1 & 0xFFFF0000u) | (f0 >> 16);
    pa.u[1] = (f3 & 0xFFFF0000u) | (f2 >> 16);
    pa.u[2] = (f5 & 0xFFFF0000u) | (f4 >> 16);
    pa.u[3] = (f7 & 0xFFFF0000u) | (f6 >> 16);
    pb.u[0] = bb.x; pb.u[1] = bb.y; pb.u[2] = bb.z; pb.u[3] = bb.w;
    acc = __builtin_amdgcn_mfma_f32_32x32x16_bf16(pa.v, pb.v, acc, 0, 0, 0);
  }
  // C/D layout (measured m74/m101): col = lane&31, row = (r&3) + 8*(r>>2) + 4*kh
  int col = w * 32 + m;
#pragma unroll
  for (int g = 0; g < 4; ++g) {
    int rowb = 8 * g + 4 * kh;  // regs 4g..4g+3 -> 4 consecutive rows
    u16 q0 = f32_to_bf16(acc[4 * g + 0]);
    u16 q1 = f32_to_bf16(acc[4 * g + 1]);
    u16 q2 = f32_to_bf16(acc[4 * g + 2]);
    u16 q3 = f32_to_bf16(acc[4 * g + 3]);
    hs[rowb + 0][col] = q0;
    hs[rowb + 1][col] = q1;
    hs[rowb + 2][col] = q2;
    hs[rowb + 3][col] = q3;
    uint2 st;
    st.x = (u32)q0 | ((u32)q1 << 16);
    st.y = (u32)q2 | ((u32)q3 << 16);
    *(uint2*)(HT + col * NN + i0 + rowb) = st;  // transposed write, 8 B/lane
  }
  for (int e = t; e < NH * FOUT; e += 256) w1l[e >> 7][e & 127] = w1s[e];
  __syncthreads();
  {
    int i = t >> 3, p = t & 7;  // 8 threads/row, 2 hidden dims each
    float s0 = b1[p], s1 = b1[p + 8];
#pragma unroll 4
    for (int f = 0; f < FOUT; ++f) {
      float hv = __uint_as_float((u32)hs[i][f] << 16);
      s0 = fmaf(hv, w1l[p][f], s0);
      s1 = fmaf(hv, w1l[p + 8][f], s1);
    }
    us[i][p] = fmaxf(s0, 0.0f);
    us[i][p + 8] = fmaxf(s1, 0.0f);
  }
  __syncthreads();
  if (t < 32) {
    float mu = b21[0], lv = b22[0];
#pragma unroll
    for (int k = 0; k < NH; ++k) {
      mu = fmaf(us[t][k], w21[k], mu);
      lv = fmaf(us[t][k], w22[k], lv);
    }
    float sp = fmaxf(lv, 0.0f) + log1pf(expf(-fabsf(lv)));  // softplus, stable
    float q = 0.5f * mu * mu - logf(sp);  // 0.5*log2pi terms cancel in qmp
#pragma unroll
    for (int off = 16; off; off >>= 1) q += __shfl_down(q, off);
    if (t == 0) qpart[blockIdx.x] = q;
  }
}

// ---------------- K3: S = adj @ h via bf16 MFMA; no LDS, no K-loop barriers.
// A-frag: adj ints direct from global, ((hi<<16)|lo)*0x3F80 -> packed bf16 {0,1}.
// B-frag: 16 B contiguous from HT row (L2-resident). deg via packed int adds.
// Epilogue: out = elu(S/deg).
__global__ __launch_bounds__(256) void attn_kernel(
    const int* __restrict__ adj, const u16* __restrict__ HT,
    float* __restrict__ out) {
  int t = threadIdx.x;
  int w = t >> 6, l = t & 63;
  int m = l & 31, kh = l >> 5;
  int i0 = blockIdx.x * 32;
  const int* ap = adj + (i0 + m) * NN + kh * 8;
  const u16* bp = HT + (w * 32 + m) * NN + kh * 8;
  f32x16 acc;
#pragma unroll
  for (int r = 0; r < 16; ++r) acc[r] = 0.0f;
  u32 degp = 0;  // packed: lo16 = sum of even-k adj, hi16 = odd-k (max 2048 each)
#pragma unroll 4
  for (int kc = 0; kc < NN; kc += 16) {
    int4 a0 = *(const int4*)ap;
    int4 a1 = *(const int4*)(ap + 4);
    uint4 bb = *(const uint4*)bp;
    ap += 16; bp += 16;
    u32 t0 = ((u32)a0.y << 16) | (u32)a0.x;
    u32 t1 = ((u32)a0.w << 16) | (u32)a0.z;
    u32 t2 = ((u32)a1.y << 16) | (u32)a1.x;
    u32 t3 = ((u32)a1.w << 16) | (u32)a1.z;
    degp += t0 + t1 + t2 + t3;
    PackAB pa, pb;
    pa.u[0] = t0 * 0x3F80u;  // {0,1} -> bf16 {0.0, 1.0}, both halves at once
    pa.u[1] = t1 * 0x3F80u;
    pa.u[2] = t2 * 0x3F80u;
    pa.u[3] = t3 * 0x3F80u;
    pb.u[0] = bb.x; pb.u[1] = bb.y; pb.u[2] = bb.z; pb.u[3] = bb.w;
    acc = __builtin_amdgcn_mfma_f32_32x32x16_bf16(pa.v, pb.v, acc, 0, 0, 0);
  }
  u32 dsum = (degp & 0xFFFFu) + (degp >> 16);  // this lane's k-half of deg[row m]
  dsum += __shfl_down(dsum, 32);               // lanes<32 now hold full deg[i0+l]
  float rdeg = (dsum > 0) ? 1.0f / (float)dsum : 0.0f;
  int col = w * 32 + m;
#pragma unroll
  for (int r = 0; r < 16; ++r) {
    int row = (r & 3) + 8 * (r >> 2) + 4 * kh;
    float rd = __shfl(rdeg, row);  // deg lives in lane 'row' (<32)
    float v = acc[r] * rd;
    out[(i0 + row) * FOUT + col] = v > 0.0f ? v : expm1f(v);
  }
}

// ---------------- K4: qmp = sum of 256 block partials -> d_out[8192*128]
__global__ __launch_bounds__(256) void qred_kernel(
    const float* __restrict__ qpart, float* __restrict__ outq) {
  __shared__ float sred[4];
  int t = threadIdx.x;
  float v = qpart[t];
#pragma unroll
  for (int off = 32; off; off >>= 1) v += __shfl_down(v, off);
  if ((t & 63) == 0) sred[t >> 6] = v;
  __syncthreads();
  if (t == 0) outq[0] = sred[0] + sred[1] + sred[2] + sred[3];
}

extern "C" void kernel_launch(void* const* d_in, const int* in_sizes, int n_in,
                              void* d_out, int out_size, void* d_ws, size_t ws_size,
                              hipStream_t stream) {
  (void)in_sizes; (void)n_in; (void)out_size; (void)ws_size;
  const float* x   = (const float*)d_in[0];
  const int*   adj = (const int*)d_in[1];
  const float* W   = (const float*)d_in[2];
  const float* w1  = (const float*)d_in[3];
  const float* b1  = (const float*)d_in[4];
  const float* w21 = (const float*)d_in[5];
  const float* b21 = (const float*)d_in[6];
  const float* w22 = (const float*)d_in[7];
  const float* b22 = (const float*)d_in[8];
  float* out = (float*)d_out;

  char* ws = (char*)d_ws;
  u16*   HT    = (u16*)ws;                                  // 2 MiB
  u16*   WT    = (u16*)(ws + (2u << 20));                   // 128 KiB
  float* w1s   = (float*)(ws + (2u << 20) + (128u << 10));  // 8 KiB
  float* qpart = (float*)(ws + (2u << 20) + (128u << 10) + (16u << 10));

  prep_kernel<<<257, 256, 0, stream>>>(W, w1, WT, w1s);
  h_kernel<<<256, 256, 0, stream>>>(x, WT, b1, w21, b21, w22, b22, w1s, HT, qpart);
  attn_kernel<<<256, 256, 0, stream>>>(adj, HT, out);
  qred_kernel<<<1, 256, 0, stream>>>(qpart, out + (size_t)NN * FOUT);
}

// Round 2
// 573.838 us; speedup vs baseline: 1.0283x; 1.0283x over previous
//
#include <hip/hip_runtime.h>

typedef unsigned int u32;
typedef unsigned short u16;

#define NN 8192
#define FIN 512
#define FOUT 128
#define NH 16

typedef float f32x16 __attribute__((ext_vector_type(16)));
typedef __bf16 bf16x8 __attribute__((ext_vector_type(8)));

union PackAB { u32 u[4]; bf16x8 v; };

__device__ __forceinline__ u32 rne_hi(u32 u) {
  return u + (0x7FFFu + ((u >> 16) & 1u));  // RNE bf16 in high half
}
__device__ __forceinline__ u16 f32_to_bf16(float f) {
  return (u16)(rne_hi(__float_as_uint(f)) >> 16);
}

// ---------------- K0: xb = bf16(x); WT = bf16(W^T); w1s = folded w1.
// grid 2305: [0,2048) x-convert (8 elems/thread), [2048,2304) WT, 2304 w1s.
__global__ __launch_bounds__(256) void prep_kernel(
    const float* __restrict__ x, const float* __restrict__ W,
    const float* __restrict__ w1, u16* __restrict__ xb,
    u16* __restrict__ WT, float* __restrict__ w1s) {
  int b = blockIdx.x, t = threadIdx.x;
  if (b < 2048) {
    int o = (b * 256 + t) * 8;
    float4 a0 = *(const float4*)(x + o);
    float4 a1 = *(const float4*)(x + o + 4);
    u32 f0 = rne_hi(__float_as_uint(a0.x)), f1 = rne_hi(__float_as_uint(a0.y));
    u32 f2 = rne_hi(__float_as_uint(a0.z)), f3 = rne_hi(__float_as_uint(a0.w));
    u32 f4 = rne_hi(__float_as_uint(a1.x)), f5 = rne_hi(__float_as_uint(a1.y));
    u32 f6 = rne_hi(__float_as_uint(a1.z)), f7 = rne_hi(__float_as_uint(a1.w));
    uint4 st;
    st.x = (f1 & 0xFFFF0000u) | (f0 >> 16);
    st.y = (f3 & 0xFFFF0000u) | (f2 >> 16);
    st.z = (f5 & 0xFFFF0000u) | (f4 >> 16);
    st.w = (f7 & 0xFFFF0000u) | (f6 >> 16);
    *(uint4*)(xb + o) = st;
  } else if (b < 2304) {
    int o = (b - 2048) * 256 + t;
    int n = o >> 9, k = o & 511;
    WT[o] = f32_to_bf16(W[k * FOUT + n]);
  } else {
    for (int e = t; e < NH * FOUT; e += 256) {
      int k = e >> 7, f = e & 127;
      w1s[e] = w1[k * 256 + f] + w1[k * 256 + 128 + f];
    }
  }
}

// ---------------- K1: Hp[chunk] += xb @ W over K-chunk. grid = 256*KSH.
__global__ __launch_bounds__(256, 4) void h_kernel(
    const u16* __restrict__ xb, const u16* __restrict__ WT,
    float* __restrict__ Hp, int KL) {
  int t = threadIdx.x;
  int w = t >> 6, l = t & 63;
  int m = l & 31, kh = l >> 5;
  int tile = blockIdx.x & 255, chunk = blockIdx.x >> 8;
  int i0 = tile * 32, k0 = chunk * KL;
  const u16* ap = xb + (size_t)(i0 + m) * FIN + k0 + kh * 8;
  const u16* bp = WT + (size_t)(w * 32 + m) * FIN + k0 + kh * 8;
  f32x16 acc;
#pragma unroll
  for (int r = 0; r < 16; ++r) acc[r] = 0.0f;
#pragma unroll 4
  for (int kc = 0; kc < KL; kc += 16) {
    uint4 aa = *(const uint4*)ap;
    uint4 bb = *(const uint4*)bp;
    ap += 16; bp += 16;
    PackAB pa, pb;
    pa.u[0] = aa.x; pa.u[1] = aa.y; pa.u[2] = aa.z; pa.u[3] = aa.w;
    pb.u[0] = bb.x; pb.u[1] = bb.y; pb.u[2] = bb.z; pb.u[3] = bb.w;
    acc = __builtin_amdgcn_mfma_f32_32x32x16_bf16(pa.v, pb.v, acc, 0, 0, 0);
  }
  float* hp = Hp + (size_t)chunk * NN * FOUT;
  int col = w * 32 + m;
#pragma unroll
  for (int r = 0; r < 16; ++r) {
    int row = (r & 3) + 8 * (r >> 2) + 4 * kh;
    hp[(size_t)(i0 + row) * FOUT + col] = acc[r];
  }
}

// ---------------- K2: h = sum(Hp) -> HT bf16 [128][8192]; fused attn-net -> qpart.
__global__ __launch_bounds__(256) void reduceH_kernel(
    const float* __restrict__ Hp, int KSH,
    const float* __restrict__ b1, const float* __restrict__ w21,
    const float* __restrict__ b21, const float* __restrict__ w22,
    const float* __restrict__ b22, const float* __restrict__ w1s,
    u16* __restrict__ HT, float* __restrict__ qpart) {
  __shared__ float hs[32][FOUT + 4];
  __shared__ float w1l[NH][FOUT + 4];
  __shared__ float us[32][NH + 1];
  int t = threadIdx.x;
  int i0 = blockIdx.x * 32;
  // sum KSH partials; thread t owns 16 contiguous elems of the 32x128 tile
  float v[16];
  const float* base = Hp + (size_t)i0 * FOUT + t * 16;
#pragma unroll
  for (int e = 0; e < 16; e += 4) {
    float4 x4 = *(const float4*)(base + e);
    v[e] = x4.x; v[e + 1] = x4.y; v[e + 2] = x4.z; v[e + 3] = x4.w;
  }
  for (int c = 1; c < KSH; ++c) {
    const float* p = base + (size_t)c * NN * FOUT;
#pragma unroll
    for (int e = 0; e < 16; e += 4) {
      float4 x4 = *(const float4*)(p + e);
      v[e] += x4.x; v[e + 1] += x4.y; v[e + 2] += x4.z; v[e + 3] += x4.w;
    }
  }
  {
    int row = t >> 3, c0 = (t & 7) * 16;
#pragma unroll
    for (int e = 0; e < 16; ++e) hs[row][c0 + e] = v[e];
  }
  for (int e = t; e < NH * FOUT; e += 256) w1l[e >> 7][e & 127] = w1s[e];
  __syncthreads();
  // HT transposed write: thread -> (col c, row-quarter q), 8 rows = 16 B store
#pragma unroll
  for (int cc = 0; cc < 2; ++cc) {
    int c = cc * 64 + (t >> 2), q = t & 3;
    u32 p[4];
#pragma unroll
    for (int j = 0; j < 4; ++j) {
      u16 lo = f32_to_bf16(hs[q * 8 + 2 * j][c]);
      u16 hi = f32_to_bf16(hs[q * 8 + 2 * j + 1][c]);
      p[j] = (u32)lo | ((u32)hi << 16);
    }
    uint4 st; st.x = p[0]; st.y = p[1]; st.z = p[2]; st.w = p[3];
    *(uint4*)(HT + (size_t)c * NN + i0 + q * 8) = st;
  }
  // u = relu(h @ w1s^T + b1)
  {
    int i = t >> 3, p = t & 7;
    float s0 = b1[p], s1 = b1[p + 8];
#pragma unroll 4
    for (int f = 0; f < FOUT; ++f) {
      float hv = hs[i][f];
      s0 = fmaf(hv, w1l[p][f], s0);
      s1 = fmaf(hv, w1l[p + 8][f], s1);
    }
    us[i][p] = fmaxf(s0, 0.0f);
    us[i][p + 8] = fmaxf(s1, 0.0f);
  }
  __syncthreads();
  if (t < 32) {
    float mu = b21[0], lv = b22[0];
#pragma unroll
    for (int k = 0; k < NH; ++k) {
      mu = fmaf(us[t][k], w21[k], mu);
      lv = fmaf(us[t][k], w22[k], lv);
    }
    float sp = fmaxf(lv, 0.0f) + log1pf(expf(-fabsf(lv)));
    float q = 0.5f * mu * mu - logf(sp);  // 0.5*log2pi terms cancel in qmp
#pragma unroll
    for (int off = 16; off; off >>= 1) q += __shfl_down(q, off);
    if (t == 0) qpart[blockIdx.x] = q;
  }
}

// ---------------- K3: Sp[chunk] = adj[:, k-chunk] @ h[k-chunk] + deg partials.
// grid = 256*KSA -> up to 32 waves/CU. No LDS, no barriers.
__global__ __launch_bounds__(256, 8) void attn_kernel(
    const int* __restrict__ adj, const u16* __restrict__ HT,
    float* __restrict__ Sp, u32* __restrict__ degw, int KL) {
  int t = threadIdx.x;
  int w = t >> 6, l = t & 63;
  int m = l & 31, kh = l >> 5;
  int tile = blockIdx.x & 255, chunk = blockIdx.x >> 8;
  int i0 = tile * 32, k0 = chunk * KL;
  const int* ap = adj + (size_t)(i0 + m) * NN + k0 + kh * 8;
  const u16* bp = HT + (size_t)(w * 32 + m) * NN + k0 + kh * 8;
  f32x16 acc;
#pragma unroll
  for (int r = 0; r < 16; ++r) acc[r] = 0.0f;
  u32 degp = 0;  // packed u16 halves; max 4096 per half, no overflow
#pragma unroll 2
  for (int kc = 0; kc < KL; kc += 16) {
    int4 a0 = *(const int4*)ap;
    int4 a1 = *(const int4*)(ap + 4);
    uint4 bb = *(const uint4*)bp;
    ap += 16; bp += 16;
    u32 t0 = ((u32)a0.y << 16) | (u32)a0.x;
    u32 t1 = ((u32)a0.w << 16) | (u32)a0.z;
    u32 t2 = ((u32)a1.y << 16) | (u32)a1.x;
    u32 t3 = ((u32)a1.w << 16) | (u32)a1.z;
    degp += t0 + t1 + t2 + t3;
    PackAB pa, pb;
    pa.u[0] = t0 * 0x3F80u;  // {0,1} -> bf16 {0.0, 1.0}
    pa.u[1] = t1 * 0x3F80u;
    pa.u[2] = t2 * 0x3F80u;
    pa.u[3] = t3 * 0x3F80u;
    pb.u[0] = bb.x; pb.u[1] = bb.y; pb.u[2] = bb.z; pb.u[3] = bb.w;
    acc = __builtin_amdgcn_mfma_f32_32x32x16_bf16(pa.v, pb.v, acc, 0, 0, 0);
  }
  u32 dsum = (degp & 0xFFFFu) + (degp >> 16);
  dsum += __shfl_down(dsum, 32);  // lanes<32: full deg over this k-chunk
  if (w == 0 && l < 32) degw[chunk * NN + i0 + l] = dsum;
  float* sp = Sp + (size_t)chunk * NN * FOUT;
  int col = w * 32 + m;
#pragma unroll
  for (int r = 0; r < 16; ++r) {
    int row = (r & 3) + 8 * (r >> 2) + 4 * kh;
    sp[(size_t)(i0 + row) * FOUT + col] = acc[r];
  }
}

// ---------------- K4: out = elu(sum(Sp)/deg). grid 1024, 4 elems/thread.
__global__ __launch_bounds__(256) void reduceS_kernel(
    const float* __restrict__ Sp, const u32* __restrict__ degw,
    float* __restrict__ out, int KSA) {
  int idx = (blockIdx.x * 256 + threadIdx.x) * 4;
  int i = idx >> 7;
  u32 deg = 0;
  for (int c = 0; c < KSA; ++c) deg += degw[c * NN + i];
  float4 s = {0.0f, 0.0f, 0.0f, 0.0f};
  for (int c = 0; c < KSA; ++c) {
    float4 v4 = *(const float4*)(Sp + (size_t)c * NN * FOUT + idx);
    s.x += v4.x; s.y += v4.y; s.z += v4.z; s.w += v4.w;
  }
  float rd = deg ? 1.0f / (float)deg : 0.0f;
  float4 o;
  o.x = s.x * rd; o.y = s.y * rd; o.z = s.z * rd; o.w = s.w * rd;
  o.x = o.x > 0.0f ? o.x : expm1f(o.x);
  o.y = o.y > 0.0f ? o.y : expm1f(o.y);
  o.z = o.z > 0.0f ? o.z : expm1f(o.z);
  o.w = o.w > 0.0f ? o.w : expm1f(o.w);
  *(float4*)(out + idx) = o;
}

// ---------------- K5: qmp = sum of 256 block partials
__global__ __launch_bounds__(256) void qred_kernel(
    const float* __restrict__ qpart, float* __restrict__ outq) {
  __shared__ float sred[4];
  int t = threadIdx.x;
  float v = qpart[t];
#pragma unroll
  for (int off = 32; off; off >>= 1) v += __shfl_down(v, off);
  if ((t & 63) == 0) sred[t >> 6] = v;
  __syncthreads();
  if (t == 0) outq[0] = sred[0] + sred[1] + sred[2] + sred[3];
}

extern "C" void kernel_launch(void* const* d_in, const int* in_sizes, int n_in,
                              void* d_out, int out_size, void* d_ws, size_t ws_size,
                              hipStream_t stream) {
  (void)in_sizes; (void)n_in; (void)out_size;
  const float* x   = (const float*)d_in[0];
  const int*   adj = (const int*)d_in[1];
  const float* W   = (const float*)d_in[2];
  const float* w1  = (const float*)d_in[3];
  const float* b1  = (const float*)d_in[4];
  const float* w21 = (const float*)d_in[5];
  const float* b21 = (const float*)d_in[6];
  const float* w22 = (const float*)d_in[7];
  const float* b22 = (const float*)d_in[8];
  float* out = (float*)d_out;

  // pick split-K factors that fit ws
  const size_t TILE4 = (size_t)NN * FOUT * 4;  // 4 MB
  int KSA = 8, KSH = 4;
  for (;;) {
    size_t need = (size_t)(KSA + KSH) * TILE4       // Sp + Hp
                + (size_t)NN * FIN * 2              // xb
                + (size_t)NN * FOUT * 2             // HT
                + (size_t)FOUT * FIN * 2            // WT
                + (size_t)KSA * NN * 4              // degw
                + NH * FOUT * 4 + 2048;             // w1s + qpart
    if (need <= ws_size || (KSA == 1 && KSH == 1)) break;
    if (KSH > 1) KSH >>= 1; else KSA >>= 1;
  }

  char* ws = (char*)d_ws;
  float* Sp   = (float*)ws;                          ws += (size_t)KSA * TILE4;
  float* Hp   = (float*)ws;                          ws += (size_t)KSH * TILE4;
  u16*   xb   = (u16*)ws;                            ws += (size_t)NN * FIN * 2;
  u16*   HT   = (u16*)ws;                            ws += (size_t)NN * FOUT * 2;
  u16*   WT   = (u16*)ws;                            ws += (size_t)FOUT * FIN * 2;
  u32*   degw = (u32*)ws;                            ws += (size_t)KSA * NN * 4;
  float* w1s  = (float*)ws;                          ws += NH * FOUT * 4;
  float* qpart= (float*)ws;

  prep_kernel<<<2305, 256, 0, stream>>>(x, W, w1, xb, WT, w1s);
  h_kernel<<<256 * KSH, 256, 0, stream>>>(xb, WT, Hp, FIN / KSH);
  reduceH_kernel<<<256, 256, 0, stream>>>(Hp, KSH, b1, w21, b21, w22, b22, w1s, HT, qpart);
  attn_kernel<<<256 * KSA, 256, 0, stream>>>(adj, HT, Sp, degw, NN / KSA);
  reduceS_kernel<<<1024, 256, 0, stream>>>(Sp, degw, out, KSA);
  qred_kernel<<<1, 256, 0, stream>>>(qpart, out + (size_t)NN * FOUT);
}

// Round 3
// 441.329 us; speedup vs baseline: 1.3371x; 1.3002x over previous
//
#include <hip/hip_runtime.h>

typedef unsigned int u32;
typedef unsigned short u16;

#define NN 8192
#define FIN 512
#define FOUT 128
#define NH 16
#define BK 64   // K-slab staged per barrier; LDS rows are BK u16, XOR-swizzled

typedef float f32x16 __attribute__((ext_vector_type(16)));
typedef __bf16 bf16x8 __attribute__((ext_vector_type(8)));

union PackAB { u32 u[4]; bf16x8 v; };

__device__ __forceinline__ u32 rne_hi(u32 u) {
  return u + (0x7FFFu + ((u >> 16) & 1u));  // RNE bf16 in high half
}
__device__ __forceinline__ u16 f32_to_bf16(float f) {
  return (u16)(rne_hi(__float_as_uint(f)) >> 16);
}

// ---------------- K0: WT = bf16(W^T) [128][512]; w1s = folded w1.
__global__ __launch_bounds__(256) void prep_kernel(
    const float* __restrict__ W, const float* __restrict__ w1,
    u16* __restrict__ WT, float* __restrict__ w1s) {
  int b = blockIdx.x, t = threadIdx.x;
  if (b < 256) {
    int o = b * 256 + t;
    int n = o >> 9, k = o & 511;
    WT[o] = f32_to_bf16(W[k * FOUT + n]);
  } else {
    for (int e = t; e < NH * FOUT; e += 256) {
      int k = e >> 7, f = e & 127;
      w1s[e] = w1[k * 256 + f] + w1[k * 256 + 128 + f];
    }
  }
}

// ---------------- K1: Hp[chunk] = x-chunk @ W-chunk. Coalesced LDS-staged MFMA.
// A: x f32 -> bf16 at stage time. B: WT rows. grid = 256 tiles * KSH chunks.
__global__ __launch_bounds__(256, 6) void h_kernel(
    const float* __restrict__ x, const u16* __restrict__ WT,
    float* __restrict__ Hp, int KL) {
  __shared__ u16 aS[32 * BK];
  __shared__ u16 bS[128 * BK];
  int t = threadIdx.x;
  int w = t >> 6, l = t & 63;
  int m = l & 31, kh = l >> 5;
  int tile = blockIdx.x & 255, chunk = blockIdx.x >> 8;
  int i0 = tile * 32, k0 = chunk * KL;

  // A staging: rows arow, arow+16; 4 f32 at col acol -> 4 bf16 (8 B, half-chunk)
  int arow = t >> 4, acol = (t & 15) * 4;
  int ac = (t & 15) >> 1, ah = t & 1;
  int aoff0 = arow * BK + ((ac ^ (arow & 7)) << 3) + ah * 4;
  int aoff1 = (arow + 16) * BK + ((ac ^ ((arow + 16) & 7)) << 3) + ah * 4;
  const float* ap0 = x + (size_t)(i0 + arow) * FIN + k0 + acol;
  const float* ap1 = ap0 + (size_t)16 * FIN;
  // B staging: rows hrow+32p, 16 B chunk hc
  int hrow = t >> 3, hc = t & 7;
  const u16* bp0 = WT + (size_t)hrow * FIN + k0 + hc * 8;
  int boff[4];
#pragma unroll
  for (int p = 0; p < 4; ++p) {
    int r = hrow + 32 * p;
    boff[p] = r * BK + ((hc ^ (r & 7)) << 3);
  }
  int aro = m * BK, am7 = m & 7;
  int nB = w * 32 + m;
  int bro = nB * BK, bm7 = nB & 7;

  f32x16 acc;
#pragma unroll
  for (int r = 0; r < 16; ++r) acc[r] = 0.0f;

  for (int o = 0; o < KL; o += BK) {
    float4 a0 = *(const float4*)ap0;
    float4 a1 = *(const float4*)ap1;
    uint4 h0 = *(const uint4*)bp0;
    uint4 h1 = *(const uint4*)(bp0 + 32 * (size_t)FIN);
    uint4 h2 = *(const uint4*)(bp0 + 64 * (size_t)FIN);
    uint4 h3 = *(const uint4*)(bp0 + 96 * (size_t)FIN);
    ap0 += BK; ap1 += BK; bp0 += BK;
    uint2 w0, w1v;
    w0.x = (rne_hi(__float_as_uint(a0.y)) & 0xFFFF0000u) | (rne_hi(__float_as_uint(a0.x)) >> 16);
    w0.y = (rne_hi(__float_as_uint(a0.w)) & 0xFFFF0000u) | (rne_hi(__float_as_uint(a0.z)) >> 16);
    w1v.x = (rne_hi(__float_as_uint(a1.y)) & 0xFFFF0000u) | (rne_hi(__float_as_uint(a1.x)) >> 16);
    w1v.y = (rne_hi(__float_as_uint(a1.w)) & 0xFFFF0000u) | (rne_hi(__float_as_uint(a1.z)) >> 16);
    *(uint2*)&aS[aoff0] = w0;
    *(uint2*)&aS[aoff1] = w1v;
    *(uint4*)&bS[boff[0]] = h0;
    *(uint4*)&bS[boff[1]] = h1;
    *(uint4*)&bS[boff[2]] = h2;
    *(uint4*)&bS[boff[3]] = h3;
    __syncthreads();
#pragma unroll
    for (int s = 0; s < BK; s += 16) {
      int cA = (s >> 3) + kh;
      PackAB pa, pb;
      pa.v = *(const bf16x8*)&aS[aro + ((cA ^ am7) << 3)];
      pb.v = *(const bf16x8*)&bS[bro + ((cA ^ bm7) << 3)];
      acc = __builtin_amdgcn_mfma_f32_32x32x16_bf16(pa.v, pb.v, acc, 0, 0, 0);
    }
    __syncthreads();
  }
  float* hp = Hp + (size_t)chunk * NN * FOUT;
  int col = w * 32 + m;
#pragma unroll
  for (int r = 0; r < 16; ++r) {
    int row = (r & 3) + 8 * (r >> 2) + 4 * kh;
    hp[(size_t)(i0 + row) * FOUT + col] = acc[r];
  }
}

// ---------------- K2: h = sum(Hp) -> HT bf16 [128][8192]; fused attn-net -> qpart.
__global__ __launch_bounds__(256) void reduceH_kernel(
    const float* __restrict__ Hp, int KSH,
    const float* __restrict__ b1, const float* __restrict__ w21,
    const float* __restrict__ b21, const float* __restrict__ w22,
    const float* __restrict__ b22, const float* __restrict__ w1s,
    u16* __restrict__ HT, float* __restrict__ qpart) {
  __shared__ float hs[32][FOUT + 4];
  __shared__ float w1l[NH][FOUT + 4];
  __shared__ float us[32][NH + 1];
  int t = threadIdx.x;
  int i0 = blockIdx.x * 32;
  float v[16];
  const float* base = Hp + (size_t)i0 * FOUT + t * 16;
#pragma unroll
  for (int e = 0; e < 16; e += 4) {
    float4 x4 = *(const float4*)(base + e);
    v[e] = x4.x; v[e + 1] = x4.y; v[e + 2] = x4.z; v[e + 3] = x4.w;
  }
  for (int c = 1; c < KSH; ++c) {
    const float* p = base + (size_t)c * NN * FOUT;
#pragma unroll
    for (int e = 0; e < 16; e += 4) {
      float4 x4 = *(const float4*)(p + e);
      v[e] += x4.x; v[e + 1] += x4.y; v[e + 2] += x4.z; v[e + 3] += x4.w;
    }
  }
  {
    int row = t >> 3, c0 = (t & 7) * 16;
#pragma unroll
    for (int e = 0; e < 16; ++e) hs[row][c0 + e] = v[e];
  }
  for (int e = t; e < NH * FOUT; e += 256) w1l[e >> 7][e & 127] = w1s[e];
  __syncthreads();
#pragma unroll
  for (int cc = 0; cc < 2; ++cc) {
    int c = cc * 64 + (t >> 2), q = t & 3;
    u32 p[4];
#pragma unroll
    for (int j = 0; j < 4; ++j) {
      u16 lo = f32_to_bf16(hs[q * 8 + 2 * j][c]);
      u16 hi = f32_to_bf16(hs[q * 8 + 2 * j + 1][c]);
      p[j] = (u32)lo | ((u32)hi << 16);
    }
    uint4 st; st.x = p[0]; st.y = p[1]; st.z = p[2]; st.w = p[3];
    *(uint4*)(HT + (size_t)c * NN + i0 + q * 8) = st;
  }
  {
    int i = t >> 3, p = t & 7;
    float s0 = b1[p], s1 = b1[p + 8];
#pragma unroll 4
    for (int f = 0; f < FOUT; ++f) {
      float hv = hs[i][f];
      s0 = fmaf(hv, w1l[p][f], s0);
      s1 = fmaf(hv, w1l[p + 8][f], s1);
    }
    us[i][p] = fmaxf(s0, 0.0f);
    us[i][p + 8] = fmaxf(s1, 0.0f);
  }
  __syncthreads();
  if (t < 32) {
    float mu = b21[0], lv = b22[0];
#pragma unroll
    for (int k = 0; k < NH; ++k) {
      mu = fmaf(us[t][k], w21[k], mu);
      lv = fmaf(us[t][k], w22[k], lv);
    }
    float sp = fmaxf(lv, 0.0f) + log1pf(expf(-fabsf(lv)));
    float q = 0.5f * mu * mu - logf(sp);  // 0.5*log2pi terms cancel in qmp
#pragma unroll
    for (int off = 16; off; off >>= 1) q += __shfl_down(q, off);
    if (t == 0) qpart[blockIdx.x] = q;
  }
}

// ---------------- K3: Sp[chunk] = adj-chunk @ h-chunk, deg partials.
// Coalesced LDS-staged MFMA; adj int->bf16 packed at stage time.
__global__ __launch_bounds__(256, 6) void attn_kernel(
    const int* __restrict__ adj, const u16* __restrict__ HT,
    float* __restrict__ Sp, u32* __restrict__ degw, int KL) {
  __shared__ u16 aS[32 * BK];
  __shared__ u16 bS[128 * BK];
  int t = threadIdx.x;
  int w = t >> 6, l = t & 63;
  int m = l & 31, kh = l >> 5;
  int tile = blockIdx.x & 255, chunk = blockIdx.x >> 8;
  int i0 = tile * 32, k0 = chunk * KL;

  int arow = t >> 4, acol = (t & 15) * 4;
  int ac = (t & 15) >> 1, ah = t & 1;
  int aoff0 = arow * BK + ((ac ^ (arow & 7)) << 3) + ah * 4;
  int aoff1 = (arow + 16) * BK + ((ac ^ ((arow + 16) & 7)) << 3) + ah * 4;
  const int* ap0 = adj + (size_t)(i0 + arow) * NN + k0 + acol;
  const int* ap1 = ap0 + (size_t)16 * NN;
  int hrow = t >> 3, hc = t & 7;
  const u16* bp0 = HT + (size_t)hrow * NN + k0 + hc * 8;
  int boff[4];
#pragma unroll
  for (int p = 0; p < 4; ++p) {
    int r = hrow + 32 * p;
    boff[p] = r * BK + ((hc ^ (r & 7)) << 3);
  }
  int aro = m * BK, am7 = m & 7;
  int nB = w * 32 + m;
  int bro = nB * BK, bm7 = nB & 7;

  f32x16 acc;
#pragma unroll
  for (int r = 0; r < 16; ++r) acc[r] = 0.0f;
  u32 degA = 0, degB = 0;  // packed u16 halves; per-half max 2*KL/BK*? << 65536

  for (int o = 0; o < KL; o += BK) {
    int4 a0 = *(const int4*)ap0;
    int4 a1 = *(const int4*)ap1;
    uint4 h0 = *(const uint4*)bp0;
    uint4 h1 = *(const uint4*)(bp0 + 32 * (size_t)NN);
    uint4 h2 = *(const uint4*)(bp0 + 64 * (size_t)NN);
    uint4 h3 = *(const uint4*)(bp0 + 96 * (size_t)NN);
    ap0 += BK; ap1 += BK; bp0 += BK;
    u32 p00 = ((u32)a0.y << 16) | (u32)a0.x;
    u32 p01 = ((u32)a0.w << 16) | (u32)a0.z;
    u32 p10 = ((u32)a1.y << 16) | (u32)a1.x;
    u32 p11 = ((u32)a1.w << 16) | (u32)a1.z;
    degA += p00 + p01;
    degB += p10 + p11;
    uint2 w0, w1v;
    w0.x = p00 * 0x3F80u; w0.y = p01 * 0x3F80u;   // {0,1} -> bf16 {0,1}
    w1v.x = p10 * 0x3F80u; w1v.y = p11 * 0x3F80u;
    *(uint2*)&aS[aoff0] = w0;
    *(uint2*)&aS[aoff1] = w1v;
    *(uint4*)&bS[boff[0]] = h0;
    *(uint4*)&bS[boff[1]] = h1;
    *(uint4*)&bS[boff[2]] = h2;
    *(uint4*)&bS[boff[3]] = h3;
    __syncthreads();
#pragma unroll
    for (int s = 0; s < BK; s += 16) {
      int cA = (s >> 3) + kh;
      PackAB pa, pb;
      pa.v = *(const bf16x8*)&aS[aro + ((cA ^ am7) << 3)];
      pb.v = *(const bf16x8*)&bS[bro + ((cA ^ bm7) << 3)];
      acc = __builtin_amdgcn_mfma_f32_32x32x16_bf16(pa.v, pb.v, acc, 0, 0, 0);
    }
    __syncthreads();
  }
  // deg: reduce 16 staging lanes per row (groups are 16 consecutive lanes)
  u32 dA = (degA & 0xFFFFu) + (degA >> 16);
  u32 dB = (degB & 0xFFFFu) + (degB >> 16);
#pragma unroll
  for (int off = 8; off; off >>= 1) {
    dA += __shfl_down(dA, off);
    dB += __shfl_down(dB, off);
  }
  if ((t & 15) == 0) {
    degw[chunk * NN + i0 + arow] = dA;
    degw[chunk * NN + i0 + arow + 16] = dB;
  }
  float* sp = Sp + (size_t)chunk * NN * FOUT;
  int col = w * 32 + m;
#pragma unroll
  for (int r = 0; r < 16; ++r) {
    int row = (r & 3) + 8 * (r >> 2) + 4 * kh;
    sp[(size_t)(i0 + row) * FOUT + col] = acc[r];
  }
}

// ---------------- K4: out = elu(sum(Sp)/deg).
__global__ __launch_bounds__(256) void reduceS_kernel(
    const float* __restrict__ Sp, const u32* __restrict__ degw,
    float* __restrict__ out, int KSA) {
  int idx = (blockIdx.x * 256 + threadIdx.x) * 4;
  int i = idx >> 7;
  u32 deg = 0;
  for (int c = 0; c < KSA; ++c) deg += degw[c * NN + i];
  float4 s = {0.0f, 0.0f, 0.0f, 0.0f};
  for (int c = 0; c < KSA; ++c) {
    float4 v4 = *(const float4*)(Sp + (size_t)c * NN * FOUT + idx);
    s.x += v4.x; s.y += v4.y; s.z += v4.z; s.w += v4.w;
  }
  float rd = deg ? 1.0f / (float)deg : 0.0f;
  float4 o;
  o.x = s.x * rd; o.y = s.y * rd; o.z = s.z * rd; o.w = s.w * rd;
  o.x = o.x > 0.0f ? o.x : expm1f(o.x);
  o.y = o.y > 0.0f ? o.y : expm1f(o.y);
  o.z = o.z > 0.0f ? o.z : expm1f(o.z);
  o.w = o.w > 0.0f ? o.w : expm1f(o.w);
  *(float4*)(out + idx) = o;
}

// ---------------- K5: qmp = sum of 256 block partials
__global__ __launch_bounds__(256) void qred_kernel(
    const float* __restrict__ qpart, float* __restrict__ outq) {
  __shared__ float sred[4];
  int t = threadIdx.x;
  float v = qpart[t];
#pragma unroll
  for (int off = 32; off; off >>= 1) v += __shfl_down(v, off);
  if ((t & 63) == 0) sred[t >> 6] = v;
  __syncthreads();
  if (t == 0) outq[0] = sred[0] + sred[1] + sred[2] + sred[3];
}

extern "C" void kernel_launch(void* const* d_in, const int* in_sizes, int n_in,
                              void* d_out, int out_size, void* d_ws, size_t ws_size,
                              hipStream_t stream) {
  (void)in_sizes; (void)n_in; (void)out_size;
  const float* x   = (const float*)d_in[0];
  const int*   adj = (const int*)d_in[1];
  const float* W   = (const float*)d_in[2];
  const float* w1  = (const float*)d_in[3];
  const float* b1  = (const float*)d_in[4];
  const float* w21 = (const float*)d_in[5];
  const float* b21 = (const float*)d_in[6];
  const float* w22 = (const float*)d_in[7];
  const float* b22 = (const float*)d_in[8];
  float* out = (float*)d_out;

  const size_t TILE4 = (size_t)NN * FOUT * 4;  // 4 MB
  int KSA = 8, KSH = 4;
  for (;;) {
    size_t need = (size_t)(KSA + KSH) * TILE4
                + (size_t)NN * FOUT * 2             // HT
                + (size_t)FOUT * FIN * 2            // WT
                + (size_t)KSA * NN * 4              // degw
                + NH * FOUT * 4 + 2048;             // w1s + qpart
    if (need <= ws_size || (KSA == 1 && KSH == 1)) break;
    if (KSH > 1) KSH >>= 1; else KSA >>= 1;
  }

  char* ws = (char*)d_ws;
  float* Sp   = (float*)ws;                          ws += (size_t)KSA * TILE4;
  float* Hp   = (float*)ws;                          ws += (size_t)KSH * TILE4;
  u16*   HT   = (u16*)ws;                            ws += (size_t)NN * FOUT * 2;
  u16*   WT   = (u16*)ws;                            ws += (size_t)FOUT * FIN * 2;
  u32*   degw = (u32*)ws;                            ws += (size_t)KSA * NN * 4;
  float* w1s  = (float*)ws;                          ws += NH * FOUT * 4;
  float* qpart= (float*)ws;

  prep_kernel<<<257, 256, 0, stream>>>(W, w1, WT, w1s);
  h_kernel<<<256 * KSH, 256, 0, stream>>>(x, WT, Hp, FIN / KSH);
  reduceH_kernel<<<256, 256, 0, stream>>>(Hp, KSH, b1, w21, b21, w22, b22, w1s, HT, qpart);
  attn_kernel<<<256 * KSA, 256, 0, stream>>>(adj, HT, Sp, degw, NN / KSA);
  reduceS_kernel<<<1024, 256, 0, stream>>>(Sp, degw, out, KSA);
  qred_kernel<<<1, 256, 0, stream>>>(qpart, out + (size_t)NN * FOUT);
}